// Round 8
// baseline (2111.294 us; speedup 1.0000x reference)
//
#include <hip/hip_runtime.h>
#include <stdint.h>

// Problem dims
#define NB   64      // batch
#define NT   256     // timesteps
#define NS   512     // input feature (state)
#define NH   1024    // hidden
#define NG   4096    // 4*NH (gates)
#define NHD  512     // dense1 width
#define NA   64      // action size
#define NO   64      // n_output

typedef float f32x4  __attribute__((ext_vector_type(4)));
typedef short bf16x8 __attribute__((ext_vector_type(8)));
typedef int   i32x4  __attribute__((ext_vector_type(4)));

__device__ __forceinline__ unsigned short f2bf(float f) {
    union { float f; unsigned u; } a; a.f = f;
    unsigned u = a.u;
    return (unsigned short)((u + 0x7fffu + ((u >> 16) & 1u)) >> 16);   // RNE
}
__device__ __forceinline__ float bf2f(unsigned short h) {
    union { unsigned u; float f; } a; a.u = ((unsigned)h) << 16; return a.f;
}
__device__ __forceinline__ float sigm(float x) {
    return __fdividef(1.0f, 1.0f + __expf(-x));
}
__device__ __forceinline__ float tanh_f(float x) {
    float e = __expf(-2.0f * fabsf(x));
    float r = __fdividef(1.0f - e, 1.0f + e);
    return x >= 0.0f ? r : -r;
}

// sc1 load: bypasses the non-coherent per-XCD L2 -> reads the coherence point.
#define GLD(dst, base, off) \
    asm volatile("global_load_dwordx4 %0, %1, off offset:" #off " sc1" \
                 : "=v"(dst) : "v"(base) : "memory")
// sc0 load: bypasses CU L1, served by the LOCAL XCD L2 (relay reads).
#define GLD0(dst, base, off) \
    asm volatile("global_load_dwordx4 %0, %1, off offset:" #off " sc0" \
                 : "=v"(dst) : "v"(base) : "memory")

// h-phase chunk (r13 layout: 1 m-tile, 4 n-tiles, Wh-lo from LDS).
// 8 h loads outstanding at phase start; chunk ks retired at vmcnt <= 7-ks
// (vmcnt retires in issue order; an older outstanding store only makes the
// wait conservative). whh from VGPR; whl from LDS per chunk. The vmcnt asm
// ties q[ks] so dependent MFMAs can't hoist above it. No #pragma in macro
// bodies (r6).
#define HKS(WN, ks)                                                              \
    {                                                                            \
        asm volatile("s_waitcnt vmcnt(" #WN ")" : "+v"(q[ks]));                  \
        union { i32x4 i; bf16x8 v; } u0; u0.i = q[ks];                           \
        bf16x8 fh = u0.v;                                                        \
        bf16x8 l0 = whl_lds[w][0][ks][lane];                                     \
        bf16x8 l1 = whl_lds[w][1][ks][lane];                                     \
        bf16x8 l2 = whl_lds[w][2][ks][lane];                                     \
        bf16x8 l3 = whl_lds[w][3][ks][lane];                                     \
        acc[0] = __builtin_amdgcn_mfma_f32_16x16x32_bf16(fh, whh[0][ks], acc[0], 0, 0, 0); \
        acc[1] = __builtin_amdgcn_mfma_f32_16x16x32_bf16(fh, whh[1][ks], acc[1], 0, 0, 0); \
        acc[2] = __builtin_amdgcn_mfma_f32_16x16x32_bf16(fh, whh[2][ks], acc[2], 0, 0, 0); \
        acc[3] = __builtin_amdgcn_mfma_f32_16x16x32_bf16(fh, whh[3][ks], acc[3], 0, 0, 0); \
        acc[0] = __builtin_amdgcn_mfma_f32_16x16x32_bf16(fh, l0, acc[0], 0, 0, 0); \
        acc[1] = __builtin_amdgcn_mfma_f32_16x16x32_bf16(fh, l1, acc[1], 0, 0, 0); \
        acc[2] = __builtin_amdgcn_mfma_f32_16x16x32_bf16(fh, l2, acc[2], 0, 0, 0); \
        acc[3] = __builtin_amdgcn_mfma_f32_16x16x32_bf16(fh, l3, acc[3], 0, 0, 0); \
    }

// Workspace layout (bytes):
//   [0)       hpk : 2 x 64 x 1024 bf16 = 262144  (h bf16-only, dbl-buffered)
//   [262144)  hF32: 64 x 1024 f32      = 262144
//   [524288)  hid : 64 x 512 f32       = 131072
//   [655360)  flags: 4 groups x 64 i32 = 1024    (global per-block flags)
//   [656384)  ecnt : 8 xcd x 4 grp i32 = 128     (leader election)
//   [656512)  lflg : 8 xcd x 4 grp x 128B = 4096 (local flags, 128B-exclusive)
//   [660608)  mbox : 8 xcd x 2 par x 4 grp x 32 KB = 2097152
//   end 2757760  -- relay only used when ws_size >= WS_NEED (r20 guard)
#define WS_HPK   0
#define WS_HF32  262144
#define WS_HID   524288
#define WS_FLG   655360
#define WS_ECNT  656384
#define WS_LFLG  656512
#define WS_MBOX  660608
#define WS_NEED  2757760

__global__ void prologue(unsigned int* __restrict__ hpk32,
                         unsigned int* __restrict__ flg32,
                         unsigned int* __restrict__ misc32,
                         unsigned int* __restrict__ mbx32,
                         int use_relay) {
    int idx = blockIdx.x * blockDim.x + threadIdx.x;   // 65536 threads
    hpk32[idx] = 0u;            // 65536 u32 = 131072 bf16 = both parities
    if (idx < 256) flg32[idx] = 0u;
    if (use_relay) {
        if (idx < 1056) misc32[idx] = 0u;   // ecnt (32) + lflg (1024)
        #pragma unroll
        for (int i = 0; i < 8; ++i) mbx32[idx + i * 65536] = 0u;
    }
}

// Persistent LSTM recurrence. Weights & x: double-bf16 hi/lo (exact);
// h exchange: bf16-ONLY (r12). 4 groups x 64 blocks (r14; r17 measured
// 5.35 us/step, total 1432).
// r20 = r18's XCD-relay made HANG-PROOF + ws-guarded. r18 failed twice
// with a new harness signature (Trio nursery); a member-poll deadlock on
// the ONE unproven HW assumption (leader plain-store dirty in local L2
// visible to member sc0 loads) could not be ruled out. Changes:
//  (a) member local-flag poll is BOUNDED (384 spins); on exhaustion the
//      block STICKILY reverts to the r17-proven protocol (global-flag
//      poll + sc1 hpack reads — always valid, identical bytes). Every
//      blocking loop is now proven-or-bounded => no deadlock possible.
//  (b) host passes use_relay = (ws_size >= WS_NEED); when 0, prologue
//      skips mailbox zeroing and ALL blocks run the exact r17 protocol
//      (r18 grew ws use 656KB -> 2.76MB without checking ws_size).
// Relay mechanism (unchanged): one LEADER per (physical XCD, group) —
// s_getreg(HW_REG_XCC_ID) + device atomicAdd (mapping-agnostic, G16) —
// polls global flags, copies the group's 32 KB h_t via sc1 into a
// per-(xcd,parity,group) mailbox with plain stores (dirty local L2),
// vmcnt(0), then sets a LOCAL flag; members poll it and read h with sc0
// (local-L2 service). sc1 broadcast: 8 MB -> 1 MB/step. Parity dbuf
// makes mailbox overwrite races impossible (leader needs global flags
// >= t+2 before touching parity t&1 again).
// r15 LESSON respected: publish window vmem-silent; relay traffic at
// step START; x-prefetch strictly AFTER the flag.
// Group g: batches [16g,16g+16) (ONE m-tile); block bi: h-cols
// [16bi,16bi+16) x 4 gates as 4 n-tiles (nt == gate); wave w: K-slice.
// Weights: whh+wx hi/lo in VGPR; Wh-lo frags in LDS (128 KB, same-wave
// same-lane -> no barrier). PLAIN launch (r2). 256 blocks == 256 CUs;
// 145 KiB LDS forces 1 block/CU.
__global__ __launch_bounds__(256, 1) void lstm_persist(
    const float* __restrict__ x, const float* __restrict__ Wx,
    const float* __restrict__ Wh, const float* __restrict__ bias,
    unsigned short* __restrict__ hpack, float* __restrict__ hF32,
    int* __restrict__ flags, int* __restrict__ ecnt,
    int* __restrict__ lflg, unsigned short* __restrict__ mbox,
    int use_relay)
{
    const int g    = blockIdx.x >> 6;    // group 0..3
    const int bi   = blockIdx.x & 63;    // block-in-group 0..63
    const int tid  = threadIdx.x;
    const int w    = tid >> 6;
    const int lane = tid & 63;
    const int lm   = lane & 15;   // A: m(batch row) ; B: n ; D: col
    const int lq   = lane >> 4;   // k-quad

    // Wh-lo fragments: [wave][nt][ks][lane] of bf16x8 = 128 KiB.
    __shared__ bf16x8 whl_lds[4][4][8][64];
    __shared__ float zl[4][4][16][17];   // [wave][nt][row][col] (+1 pad)
    __shared__ int s_role[2];            // [xcd, election rank]
    __shared__ int s_fb;                 // member per-step fallback indicator

    // ---- one-time: leader election keyed by PHYSICAL XCD ----
    if (tid == 0) {
        int xcc = 0, rank = 1;
        if (use_relay) {
            asm volatile("s_getreg_b32 %0, hwreg(HW_REG_XCC_ID)" : "=s"(xcc));
            xcc &= 7;
            rank = atomicAdd(ecnt + (xcc * 4 + g), 1);   // device-scope
        }
        s_role[0] = xcc;
        s_role[1] = rank;
    }
    __syncthreads();
    const int  xcd      = s_role[0];
    const bool isLeader = (s_role[1] == 0);      // use_relay==0 -> never
    bool useLocal       = (use_relay != 0);      // sticky per block
    // per-(xcd,group) bases
    int* const lfp = lflg + (xcd * 4 + g) * 32;            // 128 B stride
    unsigned short* const mb_par0 = mbox + (size_t)((xcd * 2 + 0) * 4 + g) * 16384;
    unsigned short* const mb_par1 = mbox + (size_t)((xcd * 2 + 1) * 4 + g) * 16384;

    // ---- one-time: weight B-fragments into registers / LDS ----
    // B-frag (16x16x32): lane holds B[k = lq*8 + j][n = lm], j = 0..7
    bf16x8 wxh[4][4], wxl[4][4];   // [nt][kstep] x-path, K=512/4waves
    bf16x8 whh[4][8];              // [nt][kstep] h-path hi, K=1024/4waves
    #pragma unroll
    for (int nt = 0; nt < 4; ++nt) {
        const int zc = nt * NH + bi * 16 + lm;   // nt == gate
        #pragma unroll
        for (int ks = 0; ks < 4; ++ks)
            #pragma unroll
            for (int j = 0; j < 8; ++j) {
                int k = w * 128 + ks * 32 + lq * 8 + j;
                float v = Wx[(size_t)k * NG + zc];
                unsigned short h = f2bf(v);
                wxh[nt][ks][j] = (short)h;
                wxl[nt][ks][j] = (short)f2bf(v - bf2f(h));
            }
        #pragma unroll
        for (int ks = 0; ks < 8; ++ks) {
            bf16x8 lo;
            #pragma unroll
            for (int j = 0; j < 8; ++j) {
                int k = w * 256 + ks * 32 + lq * 8 + j;
                float v = Wh[(size_t)k * NG + zc];
                unsigned short h = f2bf(v);
                whh[nt][ks][j] = (short)h;
                lo[j] = (short)f2bf(v - bf2f(h));
            }
            whl_lds[w][nt][ks][lane] = lo;
        }
    }

    // ---- per-thread epilogue state: threads 0..127 own 2 cells each ----
    const int et     = tid & 127;
    const int bloc   = et >> 3;          // batch-in-group 0..15
    const int prc    = et & 7;           // col-pair 0..7 (block owns 16 cols)
    const int gbatch = g * 16 + bloc;
    const int colp   = bi * 16 + prc * 2; // first col of the pair
    float bgate[2][4];
    #pragma unroll
    for (int j = 0; j < 2; ++j)
        #pragma unroll
        for (int gt = 0; gt < 4; ++gt)
            bgate[j][gt] = bias[gt * NH + colp + j];
    float c2[2] = {0.0f, 0.0f};

    int* const gflags = flags + g * 64;
    int* const myflag = gflags + bi;
    unsigned int* const hpk32 = reinterpret_cast<unsigned int*>(hpack);

    // x fragments raw fp32, loaded one step ahead: [ks][half]
    f32x4 xr[4][2];
    {
        const float* xs = x + (size_t)(g * 16 + lm) * NT * NS + w * 128 + lq * 8;
        #pragma unroll
        for (int ks = 0; ks < 4; ++ks) {
            const f32x4* p = reinterpret_cast<const f32x4*>(xs + ks * 32);
            xr[ks][0] = p[0];
            xr[ks][1] = p[1];
        }
    }

    #pragma unroll 1
    for (int t = 0; t < NT; ++t) {
        const int par = t & 1;
        unsigned short* const mb = par ? mb_par1 : mb_par0;

        if (isLeader) {
            // ---- leader: poll global flags (r14-proven pattern) ----
            if (w == 0) {
                const int* fp = gflags + lane;
                for (;;) {
                    int v = __hip_atomic_load(fp, __ATOMIC_RELAXED,
                                              __HIP_MEMORY_SCOPE_AGENT);
                    if (__all(v >= t)) break;
                    __builtin_amdgcn_s_sleep(1);
                }
            }
            __syncthreads();   // drains vmcnt for all waves
            // ---- copy group h_t (32 KB) sc1 -> local-L2 mailbox.
            // thread tid owns bytes [tid*128, tid*128+128). ----
            {
                const unsigned short* cs = hpack + (size_t)par * (NB * NH)
                                         + (size_t)g * 16384 + tid * 64;
                i32x4 c0, c1, c2r, c3, c4, c5, c6, c7;
                GLD(c0, cs, 0);  GLD(c1, cs, 16); GLD(c2r, cs, 32); GLD(c3, cs, 48);
                GLD(c4, cs, 64); GLD(c5, cs, 80); GLD(c6, cs, 96);  GLD(c7, cs, 112);
                asm volatile("s_waitcnt vmcnt(0)" ::: "memory");
                i32x4* cd = reinterpret_cast<i32x4*>(mb + tid * 64);
                cd[0] = c0; cd[1] = c1; cd[2] = c2r; cd[3] = c3;
                cd[4] = c4; cd[5] = c5; cd[6] = c6;  cd[7] = c7;
                asm volatile("s_waitcnt vmcnt(0)" ::: "memory");  // stores in L2
            }
            __syncthreads();
            if (tid == 0) *(volatile int*)lfp = t;   // plain store -> local L2
        } else {
            // ---- member: BOUNDED local-flag poll (sc0); on exhaustion,
            // sticky-revert to the r17-proven global poll. ----
            if (w == 0) {
                if (useLocal) {
                    int spins = 0;
                    for (;;) {
                        int v;
                        asm volatile("global_load_dword %0, %1, off sc0\n\t"
                                     "s_waitcnt vmcnt(0)"
                                     : "=v"(v) : "v"(lfp) : "memory");
                        if (__all(v >= t)) break;
                        if (++spins > 384) { useLocal = false; break; }
                        __builtin_amdgcn_s_sleep(1);
                    }
                }
                if (!useLocal) {
                    const int* fp = gflags + lane;
                    for (;;) {
                        int v = __hip_atomic_load(fp, __ATOMIC_RELAXED,
                                                  __HIP_MEMORY_SCOPE_AGENT);
                        if (__all(v >= t)) break;
                        __builtin_amdgcn_s_sleep(1);
                    }
                }
                if (lane == 0) s_fb = useLocal ? 0 : 1;
            }
            __syncthreads();   // drains vmcnt; publishes s_fb to all waves
        }

        // ---- issue h fragment burst: mailbox (sc0) or hpack (sc1) ----
        int fb = 0;
        if (!isLeader) fb = s_fb;
        i32x4 q[8];
        if (fb) {
            const unsigned short* hb0 = hpack + (size_t)par * (NB * NH)
                                      + (size_t)(g * 16 + lm) * NH + w * 256 + lq * 8;
            GLD(q[0], hb0, 0);   GLD(q[1], hb0, 64);
            GLD(q[2], hb0, 128); GLD(q[3], hb0, 192);
            GLD(q[4], hb0, 256); GLD(q[5], hb0, 320);
            GLD(q[6], hb0, 384); GLD(q[7], hb0, 448);
        } else {
            const unsigned short* hb0 = mb + (size_t)lm * NH + w * 256 + lq * 8;
            GLD0(q[0], hb0, 0);   GLD0(q[1], hb0, 64);
            GLD0(q[2], hb0, 128); GLD0(q[3], hb0, 192);
            GLD0(q[4], hb0, 256); GLD0(q[5], hb0, 320);
            GLD0(q[6], hb0, 384); GLD0(q[7], hb0, 448);
        }

        // ---- x-phase in the h-load shadow: hi/lo convert + 48 MFMAs ----
        f32x4 acc[4];
        #pragma unroll
        for (int nt = 0; nt < 4; ++nt) {
            acc[nt][0] = 0.f; acc[nt][1] = 0.f;
            acc[nt][2] = 0.f; acc[nt][3] = 0.f;
        }
        #pragma unroll
        for (int ks = 0; ks < 4; ++ks) {
            bf16x8 axh, axl;
            f32x4 vlo = xr[ks][0], vhi = xr[ks][1];
            #pragma unroll
            for (int j = 0; j < 4; ++j) {
                unsigned short h0 = f2bf(vlo[j]);
                axh[j]     = (short)h0;
                axl[j]     = (short)f2bf(vlo[j] - bf2f(h0));
                unsigned short h1 = f2bf(vhi[j]);
                axh[4 + j] = (short)h1;
                axl[4 + j] = (short)f2bf(vhi[j] - bf2f(h1));
            }
            #pragma unroll
            for (int nt = 0; nt < 4; ++nt) {
                acc[nt] = __builtin_amdgcn_mfma_f32_16x16x32_bf16(axh, wxh[nt][ks], acc[nt], 0, 0, 0);
                acc[nt] = __builtin_amdgcn_mfma_f32_16x16x32_bf16(axh, wxl[nt][ks], acc[nt], 0, 0, 0);
                acc[nt] = __builtin_amdgcn_mfma_f32_16x16x32_bf16(axl, wxh[nt][ks], acc[nt], 0, 0, 0);
            }
        }

        // ---- h-phase: chunked waits (8 outstanding), hi+lo MFMAs ----
        HKS(7, 0) HKS(6, 1) HKS(5, 2) HKS(4, 3)
        HKS(3, 4) HKS(2, 5) HKS(1, 6) HKS(0, 7)

        // ---- cross-wave K-reduction via LDS (D: row = lq*4+r, col = lm) ----
        #pragma unroll
        for (int nt = 0; nt < 4; ++nt)
            #pragma unroll
            for (int r = 0; r < 4; ++r)
                zl[w][nt][lq * 4 + r][lm] = acc[nt][r];
        __syncthreads();

        // ---- epilogue: threads 0..127 (waves 0,1) do 2 cells each ----
        if (tid < 128) {
            float hv[2];
            #pragma unroll
            for (int j = 0; j < 2; ++j) {
                const int n = prc * 2 + j;
                float zg[4];
                #pragma unroll
                for (int gt = 0; gt < 4; ++gt) {
                    zg[gt] = zl[0][gt][bloc][n] + zl[1][gt][bloc][n]
                           + zl[2][gt][bloc][n] + zl[3][gt][bloc][n]
                           + bgate[j][gt];
                }
                // Keras gate order: i, f, g, o
                float ig = sigm(zg[0]);
                float fg = sigm(zg[1]);
                float gg = tanh_f(zg[2]);
                float og = sigm(zg[3]);
                c2[j] = fg * c2[j] + ig * gg;
                hv[j] = og * tanh_f(c2[j]);
            }
            // pack two adjacent cols into one u32 (little-endian: low = colp)
            unsigned pk = (unsigned)f2bf(hv[0]) | ((unsigned)f2bf(hv[1]) << 16);
            const size_t po = (size_t)((t + 1) & 1) * (NB * NH / 2)
                            + (size_t)gbatch * (NH / 2) + bi * 8 + prc;
            __hip_atomic_store(hpk32 + po, pk, __ATOMIC_RELAXED, __HIP_MEMORY_SCOPE_AGENT);
            if (t == NT - 1) {
                hF32[(size_t)gbatch * NH + colp]     = hv[0];
                hF32[(size_t)gbatch * NH + colp + 1] = hv[1];
            }
        }

        // ---- publish: syncthreads drains vmcnt (h store at coherence point),
        // then relaxed flag store — no fences, no other vmem in this window ----
        __syncthreads();
        if (tid == 0)
            __hip_atomic_store(myflag, t + 1, __ATOMIC_RELAXED, __HIP_MEMORY_SCOPE_AGENT);

        // ---- x-prefetch for t+1 strictly AFTER publish (r8/r15 lesson) ----
        if (t + 1 < NT) {
            const float* xs = x + ((size_t)(g * 16 + lm) * NT + (t + 1)) * NS
                                + w * 128 + lq * 8;
            #pragma unroll
            for (int ks = 0; ks < 4; ++ks) {
                const f32x4* p = reinterpret_cast<const f32x4*>(xs + ks * 32);
                xr[ks][0] = p[0];
                xr[ks][1] = p[1];
            }
        }
    }
}

// hid = relu(hF32 @ Wd1 + bd1)   [64,1024]x[1024,512]
// r15 heads kept (measured good). 64 blocks x 512 threads.
__global__ __launch_bounds__(512) void head1(
    const float* __restrict__ hF32, const float* __restrict__ Wd1,
    const float* __restrict__ bd1, float* __restrict__ hid)
{
    int b = blockIdx.x;
    int n = threadIdx.x;
    const float* hrow = hF32 + (size_t)b * NH;
    float acc = bd1[n];
    #pragma unroll 8
    for (int k = 0; k < NH; ++k)
        acc += hrow[k] * Wd1[(size_t)k * NHD + n];
    hid[(size_t)b * NHD + n] = fmaxf(acc, 0.0f);
}

// out = [hid | actions | horizon] @ Wd2 + bd2   K = 512 + 64 + 1 = 577
// 64 blocks x 256 threads; K split 4-way across thread groups + LDS reduce.
__global__ __launch_bounds__(256) void head2(
    const float* __restrict__ hid, const float* __restrict__ act,
    const float* __restrict__ hor, const float* __restrict__ Wd2,
    const float* __restrict__ bd2, float* __restrict__ out)
{
    __shared__ float red[4][64];
    int b  = blockIdx.x;
    int n  = threadIdx.x & 63;
    int ks = threadIdx.x >> 6;    // 0..3
    const float* hrow = hid + (size_t)b * NHD;
    float acc = 0.0f;
    #pragma unroll 4
    for (int k = ks * 128; k < ks * 128 + 128; ++k)
        acc += hrow[k] * Wd2[(size_t)k * NO + n];
    if (ks == 1) {
        const float* arow = act + (size_t)b * NA;
        #pragma unroll 4
        for (int k = 0; k < NA; ++k)
            acc += arow[k] * Wd2[(size_t)(NHD + k) * NO + n];
    }
    if (ks == 2) acc += hor[b] * Wd2[(size_t)576 * NO + n];
    if (ks == 0) acc += bd2[n];
    red[ks][n] = acc;
    __syncthreads();
    if (threadIdx.x < 64)
        out[(size_t)b * NO + n] = red[0][n] + red[1][n] + red[2][n] + red[3][n];
}

extern "C" void kernel_launch(void* const* d_in, const int* in_sizes, int n_in,
                              void* d_out, int out_size, void* d_ws, size_t ws_size,
                              hipStream_t stream)
{
    (void)in_sizes; (void)n_in; (void)out_size;
    const float* x    = (const float*)d_in[0];
    const float* act  = (const float*)d_in[1];
    const float* hor  = (const float*)d_in[2];
    const float* Wx   = (const float*)d_in[3];
    const float* Wh   = (const float*)d_in[4];
    const float* bias = (const float*)d_in[5];
    const float* Wd1  = (const float*)d_in[6];
    const float* bd1  = (const float*)d_in[7];
    const float* Wd2  = (const float*)d_in[8];
    const float* bd2  = (const float*)d_in[9];
    float* out = (float*)d_out;

    char* wsb = (char*)d_ws;
    unsigned short* hpk  = (unsigned short*)(wsb + WS_HPK);
    float* hF32 = (float*)(wsb + WS_HF32);
    float* hid  = (float*)(wsb + WS_HID);
    int*   flg  = (int*)(wsb + WS_FLG);
    int*   ecn  = (int*)(wsb + WS_ECNT);
    int*   lfl  = (int*)(wsb + WS_LFLG);
    unsigned short* mbx = (unsigned short*)(wsb + WS_MBOX);

    const int use_relay = (ws_size >= (size_t)WS_NEED) ? 1 : 0;

    prologue<<<256, 256, 0, stream>>>((unsigned int*)(wsb + WS_HPK),
                                      (unsigned int*)(wsb + WS_FLG),
                                      (unsigned int*)(wsb + WS_ECNT),
                                      (unsigned int*)(wsb + WS_MBOX),
                                      use_relay);

    // Plain launch (NOT cooperative — see r2 post-mortem). 256 blocks == 256 CUs.
    lstm_persist<<<dim3(256), dim3(256), 0, stream>>>(x, Wx, Wh, bias,
                                                      hpk, hF32, flg,
                                                      ecn, lfl, mbx, use_relay);

    head1<<<64, 512, 0, stream>>>(hF32, Wd1, bd1, hid);
    head2<<<64, 256, 0, stream>>>(hid, act, hor, Wd2, bd2, out);
}

// Round 9
// 1432.227 us; speedup vs baseline: 1.4741x; 1.4741x over previous
//
#include <hip/hip_runtime.h>
#include <stdint.h>

// Problem dims
#define NB   64      // batch
#define NT   256     // timesteps
#define NS   512     // input feature (state)
#define NH   1024    // hidden
#define NG   4096    // 4*NH (gates)
#define NHD  512     // dense1 width
#define NA   64      // action size
#define NO   64      // n_output

typedef float f32x4  __attribute__((ext_vector_type(4)));
typedef short bf16x8 __attribute__((ext_vector_type(8)));
typedef int   i32x4  __attribute__((ext_vector_type(4)));

__device__ __forceinline__ unsigned short f2bf(float f) {
    union { float f; unsigned u; } a; a.f = f;
    unsigned u = a.u;
    return (unsigned short)((u + 0x7fffu + ((u >> 16) & 1u)) >> 16);   // RNE
}
__device__ __forceinline__ float bf2f(unsigned short h) {
    union { unsigned u; float f; } a; a.u = ((unsigned)h) << 16; return a.f;
}
__device__ __forceinline__ float sigm(float x) {
    return __fdividef(1.0f, 1.0f + __expf(-x));
}
__device__ __forceinline__ float tanh_f(float x) {
    float e = __expf(-2.0f * fabsf(x));
    float r = __fdividef(1.0f - e, 1.0f + e);
    return x >= 0.0f ? r : -r;
}

// sc1 load: bypasses the non-coherent per-XCD L2 -> reads the coherence point.
#define GLD(dst, base, off) \
    asm volatile("global_load_dwordx4 %0, %1, off offset:" #off " sc1" \
                 : "=v"(dst) : "v"(base) : "memory")

// h-phase chunk (r13 layout: 1 m-tile, 4 n-tiles, Wh-lo from LDS).
// 8 h loads outstanding at phase start; chunk ks retired at vmcnt <= 7-ks.
// whh from VGPR; whl read per-chunk from LDS (4x ds_read_b128, hidden
// behind the inter-chunk sc1 return gaps; compiler inserts the lgkmcnt
// before MFMA use). The vmcnt asm ties q[ks] so the dependent MFMAs
// can't hoist above it. No #pragma in macro bodies (r6).
#define HKS(WN, ks)                                                              \
    {                                                                            \
        asm volatile("s_waitcnt vmcnt(" #WN ")" : "+v"(q[ks]));                  \
        union { i32x4 i; bf16x8 v; } u0; u0.i = q[ks];                           \
        bf16x8 fh = u0.v;                                                        \
        bf16x8 l0 = whl_lds[w][0][ks][lane];                                     \
        bf16x8 l1 = whl_lds[w][1][ks][lane];                                     \
        bf16x8 l2 = whl_lds[w][2][ks][lane];                                     \
        bf16x8 l3 = whl_lds[w][3][ks][lane];                                     \
        acc[0] = __builtin_amdgcn_mfma_f32_16x16x32_bf16(fh, whh[0][ks], acc[0], 0, 0, 0); \
        acc[1] = __builtin_amdgcn_mfma_f32_16x16x32_bf16(fh, whh[1][ks], acc[1], 0, 0, 0); \
        acc[2] = __builtin_amdgcn_mfma_f32_16x16x32_bf16(fh, whh[2][ks], acc[2], 0, 0, 0); \
        acc[3] = __builtin_amdgcn_mfma_f32_16x16x32_bf16(fh, whh[3][ks], acc[3], 0, 0, 0); \
        acc[0] = __builtin_amdgcn_mfma_f32_16x16x32_bf16(fh, l0, acc[0], 0, 0, 0); \
        acc[1] = __builtin_amdgcn_mfma_f32_16x16x32_bf16(fh, l1, acc[1], 0, 0, 0); \
        acc[2] = __builtin_amdgcn_mfma_f32_16x16x32_bf16(fh, l2, acc[2], 0, 0, 0); \
        acc[3] = __builtin_amdgcn_mfma_f32_16x16x32_bf16(fh, l3, acc[3], 0, 0, 0); \
    }

// Workspace layout (bytes):
//   [0)       hpk : 2 x 64 x 1024 bf16 = 262144  (h bf16-only, dbl-buffered)
//   [262144)  hF32: 64 x 1024 f32      = 262144
//   [524288)  hid : 64 x 512 f32       = 131072
//   [655360)  flags: 4 groups x 64 i32 = 1024
#define WS_HPK   0
#define WS_HF32  262144
#define WS_HID   524288
#define WS_FLG   655360

__global__ void prologue(unsigned int* __restrict__ hpk32,
                         unsigned int* __restrict__ flg32) {
    int idx = blockIdx.x * blockDim.x + threadIdx.x;   // 65536 threads
    hpk32[idx] = 0u;            // 65536 u32 = 131072 bf16 = both parities
    if (idx < 256) flg32[idx] = 0u;
}

// Persistent LSTM recurrence. Weights & x: double-bf16 hi/lo (exact);
// h exchange: bf16-ONLY (r12). 4 groups x 64 blocks (r13/r14).
// r21 = byte-exact revert to r17 (the best-measured kernel: 1432 us
// total, lstm 1371 us = 5.35 us/step, round 5).
// SESSION VERDICT on the 5.35 us/step floor: it is LATENCY-bound on the
// cross-XCD sync chain (publish -> flag visibility -> sc1 h read), not
// bandwidth-bound. Both structural attacks measured NEGATIVE:
//   r15 per-wave early publish: +1.6 us/step (vmem traffic in the
//       publish window delays the gating store-ack; r11/r15 lesson);
//   r20 XCD-relay L2 multicast: +2.65 us/step (extra serial hop on the
//       h path; bytes were never the binding constraint — r12/r14's
//       gains were per-block load-count/latency, not aggregate BW).
// Byte-shaving below bf16-h risks the absmax budget (0.0078125 is the
// bf16-h quantization floor). This protocol is the measured optimum.
// Group g: batches [16g,16g+16) (ONE m-tile); block bi: h-cols
// [16bi,16bi+16) x 4 gates as 4 n-tiles (nt == gate); wave w: K-slice.
// Weight storage: whh+wx hi/lo in VGPR (256); Wh-lo frags in LDS (128 KB,
// same-wave same-lane write/read -> no barrier).
// PLAIN launch (cooperative fails silently — r2). 256 blocks == 256 CUs;
// 145 KiB LDS forces 1 block/CU.
__global__ __launch_bounds__(256, 1) void lstm_persist(
    const float* __restrict__ x, const float* __restrict__ Wx,
    const float* __restrict__ Wh, const float* __restrict__ bias,
    unsigned short* __restrict__ hpack, float* __restrict__ hF32,
    int* __restrict__ flags)
{
    const int g    = blockIdx.x >> 6;    // group 0..3
    const int bi   = blockIdx.x & 63;    // block-in-group 0..63
    const int tid  = threadIdx.x;
    const int w    = tid >> 6;
    const int lane = tid & 63;
    const int lm   = lane & 15;   // A: m(batch row) ; B: n ; D: col
    const int lq   = lane >> 4;   // k-quad

    // Wh-lo fragments: [wave][nt][ks][lane] of bf16x8 = 128 KiB.
    // Each wave reads ONLY its own [w] slice -> no barrier needed.
    __shared__ bf16x8 whl_lds[4][4][8][64];
    __shared__ float zl[4][4][16][17];   // [wave][nt][row][col] (+1 pad)

    // ---- one-time: weight B-fragments into registers / LDS ----
    // B-frag (16x16x32): lane holds B[k = lq*8 + j][n = lm], j = 0..7
    bf16x8 wxh[4][4], wxl[4][4];   // [nt][kstep] x-path, K=512/4waves
    bf16x8 whh[4][8];              // [nt][kstep] h-path hi, K=1024/4waves
    #pragma unroll
    for (int nt = 0; nt < 4; ++nt) {
        const int zc = nt * NH + bi * 16 + lm;   // nt == gate
        #pragma unroll
        for (int ks = 0; ks < 4; ++ks)
            #pragma unroll
            for (int j = 0; j < 8; ++j) {
                int k = w * 128 + ks * 32 + lq * 8 + j;
                float v = Wx[(size_t)k * NG + zc];
                unsigned short h = f2bf(v);
                wxh[nt][ks][j] = (short)h;
                wxl[nt][ks][j] = (short)f2bf(v - bf2f(h));
            }
        #pragma unroll
        for (int ks = 0; ks < 8; ++ks) {
            bf16x8 lo;
            #pragma unroll
            for (int j = 0; j < 8; ++j) {
                int k = w * 256 + ks * 32 + lq * 8 + j;
                float v = Wh[(size_t)k * NG + zc];
                unsigned short h = f2bf(v);
                whh[nt][ks][j] = (short)h;
                lo[j] = (short)f2bf(v - bf2f(h));
            }
            whl_lds[w][nt][ks][lane] = lo;
        }
    }

    // ---- per-thread epilogue state: threads 0..127 own 2 cells each ----
    // Block owns 16 batches x 16 h-cols = 256 cells.
    const int et     = tid & 127;
    const int bloc   = et >> 3;          // batch-in-group 0..15
    const int prc    = et & 7;           // col-pair 0..7 (block owns 16 cols)
    const int gbatch = g * 16 + bloc;
    const int colp   = bi * 16 + prc * 2; // first col of the pair
    float bgate[2][4];
    #pragma unroll
    for (int j = 0; j < 2; ++j)
        #pragma unroll
        for (int gt = 0; gt < 4; ++gt)
            bgate[j][gt] = bias[gt * NH + colp + j];
    float c2[2] = {0.0f, 0.0f};

    int* const gflags = flags + g * 64;
    int* const myflag = gflags + bi;
    unsigned int* const hpk32 = reinterpret_cast<unsigned int*>(hpack);

    // x fragments raw fp32, loaded one step ahead: [ks][half]
    f32x4 xr[4][2];
    {
        const float* xs = x + (size_t)(g * 16 + lm) * NT * NS + w * 128 + lq * 8;
        #pragma unroll
        for (int ks = 0; ks < 4; ++ks) {
            const f32x4* p = reinterpret_cast<const f32x4*>(xs + ks * 32);
            xr[ks][0] = p[0];
            xr[ks][1] = p[1];
        }
    }

    #pragma unroll 1
    for (int t = 0; t < NT; ++t) {
        // ---- wait for h_t: ONLY wave0 polls (256 pollers device-wide;
        // all-wave polling saturates the coherence path — r10). 64 flags
        // per group -> one 4B flag per lane. The poll's own waits also
        // drain the x loads issued after last publish. ----
        if (w == 0) {
            const int* fp = gflags + lane;
            for (;;) {
                int v = __hip_atomic_load(fp, __ATOMIC_RELAXED,
                                          __HIP_MEMORY_SCOPE_AGENT);
                if (__all(v >= t)) break;
                __builtin_amdgcn_s_sleep(1);
            }
            // no fence: h loads below are sc1 (coherent past L2)
        }
        __syncthreads();   // drains vmcnt for all waves

        // ---- issue h sc1 burst: 8 x dwordx4 (bf16-only, 8 elems each) ----
        const unsigned short* hb0 = hpack + (size_t)(t & 1) * (NB * NH)
                                  + (size_t)(g * 16 + lm) * NH + w * 256 + lq * 8;
        i32x4 q[8];
        GLD(q[0], hb0, 0);   GLD(q[1], hb0, 64);
        GLD(q[2], hb0, 128); GLD(q[3], hb0, 192);
        GLD(q[4], hb0, 256); GLD(q[5], hb0, 320);
        GLD(q[6], hb0, 384); GLD(q[7], hb0, 448);

        // ---- x-phase in the h-load shadow: hi/lo convert + 48 MFMAs ----
        f32x4 acc[4];
        #pragma unroll
        for (int nt = 0; nt < 4; ++nt) {
            acc[nt][0] = 0.f; acc[nt][1] = 0.f;
            acc[nt][2] = 0.f; acc[nt][3] = 0.f;
        }
        #pragma unroll
        for (int ks = 0; ks < 4; ++ks) {
            bf16x8 axh, axl;
            f32x4 vlo = xr[ks][0], vhi = xr[ks][1];
            #pragma unroll
            for (int j = 0; j < 4; ++j) {
                unsigned short h0 = f2bf(vlo[j]);
                axh[j]     = (short)h0;
                axl[j]     = (short)f2bf(vlo[j] - bf2f(h0));
                unsigned short h1 = f2bf(vhi[j]);
                axh[4 + j] = (short)h1;
                axl[4 + j] = (short)f2bf(vhi[j] - bf2f(h1));
            }
            #pragma unroll
            for (int nt = 0; nt < 4; ++nt) {
                acc[nt] = __builtin_amdgcn_mfma_f32_16x16x32_bf16(axh, wxh[nt][ks], acc[nt], 0, 0, 0);
                acc[nt] = __builtin_amdgcn_mfma_f32_16x16x32_bf16(axh, wxl[nt][ks], acc[nt], 0, 0, 0);
                acc[nt] = __builtin_amdgcn_mfma_f32_16x16x32_bf16(axl, wxh[nt][ks], acc[nt], 0, 0, 0);
            }
        }

        // ---- h-phase: chunked waits (8 outstanding), hi+lo MFMAs ----
        HKS(7, 0) HKS(6, 1) HKS(5, 2) HKS(4, 3)
        HKS(3, 4) HKS(2, 5) HKS(1, 6) HKS(0, 7)

        // ---- cross-wave K-reduction via LDS (D: row = lq*4+r, col = lm) ----
        #pragma unroll
        for (int nt = 0; nt < 4; ++nt)
            #pragma unroll
            for (int r = 0; r < 4; ++r)
                zl[w][nt][lq * 4 + r][lm] = acc[nt][r];
        __syncthreads();

        // ---- epilogue: threads 0..127 (waves 0,1) do 2 cells each ----
        if (tid < 128) {
            float hv[2];
            #pragma unroll
            for (int j = 0; j < 2; ++j) {
                const int n = prc * 2 + j;
                float zg[4];
                #pragma unroll
                for (int gt = 0; gt < 4; ++gt) {
                    zg[gt] = zl[0][gt][bloc][n] + zl[1][gt][bloc][n]
                           + zl[2][gt][bloc][n] + zl[3][gt][bloc][n]
                           + bgate[j][gt];
                }
                // Keras gate order: i, f, g, o
                float ig = sigm(zg[0]);
                float fg = sigm(zg[1]);
                float gg = tanh_f(zg[2]);
                float og = sigm(zg[3]);
                c2[j] = fg * c2[j] + ig * gg;
                hv[j] = og * tanh_f(c2[j]);
            }
            // pack two adjacent cols into one u32 (little-endian: low = colp)
            unsigned pk = (unsigned)f2bf(hv[0]) | ((unsigned)f2bf(hv[1]) << 16);
            const size_t po = (size_t)((t + 1) & 1) * (NB * NH / 2)
                            + (size_t)gbatch * (NH / 2) + bi * 8 + prc;
            __hip_atomic_store(hpk32 + po, pk, __ATOMIC_RELAXED, __HIP_MEMORY_SCOPE_AGENT);
            if (t == NT - 1) {
                hF32[(size_t)gbatch * NH + colp]     = hv[0];
                hF32[(size_t)gbatch * NH + colp + 1] = hv[1];
            }
        }

        // ---- publish: syncthreads drains vmcnt (h store at coherence point),
        // then relaxed flag store — no fences ----
        __syncthreads();
        if (tid == 0)
            __hip_atomic_store(myflag, t + 1, __ATOMIC_RELAXED, __HIP_MEMORY_SCOPE_AGENT);

        // ---- x-prefetch for t+1 AFTER publish (r8 placement: flies during
        // the spin window; drained by the next poll/barrier) ----
        if (t + 1 < NT) {
            const float* xs = x + ((size_t)(g * 16 + lm) * NT + (t + 1)) * NS
                                + w * 128 + lq * 8;
            #pragma unroll
            for (int ks = 0; ks < 4; ++ks) {
                const f32x4* p = reinterpret_cast<const f32x4*>(xs + ks * 32);
                xr[ks][0] = p[0];
                xr[ks][1] = p[1];
            }
        }
    }
}

// hid = relu(hF32 @ Wd1 + bd1)   [64,1024]x[1024,512]
// r15 heads kept (measured good: non-lstm time 125 -> 91 us).
// 64 blocks x 512 threads (1 batch/block, thread = output col).
__global__ __launch_bounds__(512) void head1(
    const float* __restrict__ hF32, const float* __restrict__ Wd1,
    const float* __restrict__ bd1, float* __restrict__ hid)
{
    int b = blockIdx.x;
    int n = threadIdx.x;
    const float* hrow = hF32 + (size_t)b * NH;
    float acc = bd1[n];
    #pragma unroll 8
    for (int k = 0; k < NH; ++k)
        acc += hrow[k] * Wd1[(size_t)k * NHD + n];
    hid[(size_t)b * NHD + n] = fmaxf(acc, 0.0f);
}

// out = [hid | actions | horizon] @ Wd2 + bd2   K = 512 + 64 + 1 = 577
// 64 blocks x 256 threads; K split 4-way across thread groups + LDS reduce.
__global__ __launch_bounds__(256) void head2(
    const float* __restrict__ hid, const float* __restrict__ act,
    const float* __restrict__ hor, const float* __restrict__ Wd2,
    const float* __restrict__ bd2, float* __restrict__ out)
{
    __shared__ float red[4][64];
    int b  = blockIdx.x;
    int n  = threadIdx.x & 63;
    int ks = threadIdx.x >> 6;    // 0..3
    const float* hrow = hid + (size_t)b * NHD;
    float acc = 0.0f;
    #pragma unroll 4
    for (int k = ks * 128; k < ks * 128 + 128; ++k)
        acc += hrow[k] * Wd2[(size_t)k * NO + n];
    if (ks == 1) {
        const float* arow = act + (size_t)b * NA;
        #pragma unroll 4
        for (int k = 0; k < NA; ++k)
            acc += arow[k] * Wd2[(size_t)(NHD + k) * NO + n];
    }
    if (ks == 2) acc += hor[b] * Wd2[(size_t)576 * NO + n];
    if (ks == 0) acc += bd2[n];
    red[ks][n] = acc;
    __syncthreads();
    if (threadIdx.x < 64)
        out[(size_t)b * NO + n] = red[0][n] + red[1][n] + red[2][n] + red[3][n];
}

extern "C" void kernel_launch(void* const* d_in, const int* in_sizes, int n_in,
                              void* d_out, int out_size, void* d_ws, size_t ws_size,
                              hipStream_t stream)
{
    (void)in_sizes; (void)n_in; (void)out_size; (void)ws_size;
    const float* x    = (const float*)d_in[0];
    const float* act  = (const float*)d_in[1];
    const float* hor  = (const float*)d_in[2];
    const float* Wx   = (const float*)d_in[3];
    const float* Wh   = (const float*)d_in[4];
    const float* bias = (const float*)d_in[5];
    const float* Wd1  = (const float*)d_in[6];
    const float* bd1  = (const float*)d_in[7];
    const float* Wd2  = (const float*)d_in[8];
    const float* bd2  = (const float*)d_in[9];
    float* out = (float*)d_out;

    char* wsb = (char*)d_ws;
    unsigned short* hpk = (unsigned short*)(wsb + WS_HPK);
    float* hF32 = (float*)(wsb + WS_HF32);
    float* hid  = (float*)(wsb + WS_HID);
    int*   flg  = (int*)(wsb + WS_FLG);

    prologue<<<256, 256, 0, stream>>>((unsigned int*)(wsb + WS_HPK),
                                      (unsigned int*)(wsb + WS_FLG));

    // Plain launch (NOT cooperative — see r2 post-mortem). 256 blocks == 256 CUs.
    lstm_persist<<<dim3(256), dim3(256), 0, stream>>>(x, Wx, Wh, bias,
                                                      hpk, hF32, flg);

    head1<<<64, 512, 0, stream>>>(hF32, Wd1, bd1, hid);
    head2<<<64, 256, 0, stream>>>(hid, act, hor, Wd2, bd2, out);
}